// Round 1
// baseline (435.407 us; speedup 1.0000x reference)
//
#include <hip/hip_runtime.h>
#include <hip/hip_bf16.h>
#include <math.h>

// Problem constants (from reference)
#define N_Q 4096
#define M_K 8192
#define D_DIM 512
#define P_IDX 4
#define INV_TEMP 10.0f

// GEMM tiling
#define BM 128
#define BN 128
#define KT 16
#define NCHUNK (M_K / BN)   // 64 column chunks per row
#define LDSS (BM + 4)       // 132 floats: 16B-aligned rows, bank stride 4

// ---------------------------------------------------------------------------
// Kernel A: fused fp32 GEMM tile + scale + ignore-mask + per-chunk
// {max, sumexp, argmax} partials.  Grid: (N/BM, M/BN), block 256 (16x16),
// 8x8 outputs per thread.
// ---------------------------------------------------------------------------
__global__ __launch_bounds__(256)
void scores_kernel(const float* __restrict__ Q, const float* __restrict__ K,
                   const int* __restrict__ ign, float4* __restrict__ part)
{
    __shared__ float Qs[KT][LDSS];
    __shared__ float Ks[KT][LDSS];
    __shared__ int ign_s[BM][P_IDX];

    const int tid = threadIdx.x;
    const int tx = tid & 15;
    const int ty = tid >> 4;
    const int row0 = blockIdx.x * BM;
    const int col0 = blockIdx.y * BN;

    // stage ignore indices (BM*P = 512 ints, 2 per thread)
#pragma unroll
    for (int it = 0; it < 2; ++it) {
        int idx = tid + it * 256;
        ign_s[idx >> 2][idx & 3] = ign[(row0 + (idx >> 2)) * P_IDX + (idx & 3)];
    }

    float acc[8][8];
#pragma unroll
    for (int i = 0; i < 8; ++i)
#pragma unroll
        for (int j = 0; j < 8; ++j) acc[i][j] = 0.f;

    for (int k0 = 0; k0 < D_DIM; k0 += KT) {
        __syncthreads();
        // load BM x KT tiles of Q and K, transposed into LDS [k][row]
#pragma unroll
        for (int it = 0; it < 2; ++it) {
            int idx = tid + it * 256;          // 0..511
            int r = idx >> 2;                  // 0..127
            int kv = idx & 3;                  // which float4 along k
            float4 qv = *(const float4*)&Q[(size_t)(row0 + r) * D_DIM + k0 + kv * 4];
            float4 kk4 = *(const float4*)&K[(size_t)(col0 + r) * D_DIM + k0 + kv * 4];
            Qs[kv * 4 + 0][r] = qv.x; Qs[kv * 4 + 1][r] = qv.y;
            Qs[kv * 4 + 2][r] = qv.z; Qs[kv * 4 + 3][r] = qv.w;
            Ks[kv * 4 + 0][r] = kk4.x; Ks[kv * 4 + 1][r] = kk4.y;
            Ks[kv * 4 + 2][r] = kk4.z; Ks[kv * 4 + 3][r] = kk4.w;
        }
        __syncthreads();
#pragma unroll
        for (int kk = 0; kk < KT; ++kk) {
            float4 a0 = *(const float4*)&Qs[kk][ty * 8];
            float4 a1 = *(const float4*)&Qs[kk][ty * 8 + 4];
            float4 b0 = *(const float4*)&Ks[kk][tx * 8];
            float4 b1 = *(const float4*)&Ks[kk][tx * 8 + 4];
            float ar[8] = {a0.x, a0.y, a0.z, a0.w, a1.x, a1.y, a1.z, a1.w};
            float br[8] = {b0.x, b0.y, b0.z, b0.w, b1.x, b1.y, b1.z, b1.w};
#pragma unroll
            for (int i = 0; i < 8; ++i)
#pragma unroll
                for (int j = 0; j < 8; ++j)
                    acc[i][j] = fmaf(ar[i], br[j], acc[i][j]);
        }
    }

    // Epilogue: per-row chunk reduction across the 16 tx-lanes
#pragma unroll
    for (int i = 0; i < 8; ++i) {
        const int rl = ty * 8 + i;
        const int grow = row0 + rl;
        const int ig0 = ign_s[rl][0], ig1 = ign_s[rl][1];
        const int ig2 = ign_s[rl][2], ig3 = ign_s[rl][3];
        float v[8];
        float bm = -INFINITY; int bi = 0x7fffffff;
#pragma unroll
        for (int j = 0; j < 8; ++j) {
            const int gc = col0 + tx * 8 + j;
            float x = acc[i][j] * INV_TEMP;
            if (gc == ig0 || gc == ig1 || gc == ig2 || gc == ig3) x = -INFINITY;
            v[j] = x;
            if (x > bm) { bm = x; bi = gc; }
        }
        // width-16 xor-reduce: chunk max + first-occurrence argmax
#pragma unroll
        for (int off = 8; off >= 1; off >>= 1) {
            float om = __shfl_xor(bm, off, 16);
            int oi = __shfl_xor(bi, off, 16);
            if (om > bm || (om == bm && oi < bi)) { bm = om; bi = oi; }
        }
        float se = 0.f;
#pragma unroll
        for (int j = 0; j < 8; ++j) se += expf(v[j] - bm);  // exp(-inf)=0 for masked
#pragma unroll
        for (int off = 8; off >= 1; off >>= 1) se += __shfl_xor(se, off, 16);
        if (tx == 0)
            part[(size_t)grow * NCHUNK + blockIdx.y] =
                make_float4(bm, se, __int_as_float(bi), 0.f);
    }
}

// ---------------------------------------------------------------------------
// Kernel B: one wave per row.  Merge 64 chunk partials -> lse + argmax;
// compute positive-scores directly (with duplicate dedup); write logp and
// corrects.
// ---------------------------------------------------------------------------
__global__ __launch_bounds__(64)
void combine_kernel(const float4* __restrict__ part,
                    const float* __restrict__ Q, const float* __restrict__ K,
                    const int* __restrict__ pos,
                    float* __restrict__ logp, float* __restrict__ corrects)
{
    const int row = blockIdx.x;
    const int lane = threadIdx.x;

    float4 pc = part[(size_t)row * NCHUNK + lane];
    float m = pc.x, s = pc.y;
    float av = pc.x; int ai = __float_as_int(pc.z);
#pragma unroll
    for (int off = 32; off >= 1; off >>= 1) {
        float om = __shfl_xor(m, off);
        float os = __shfl_xor(s, off);
        float oav = __shfl_xor(av, off);
        int oi = __shfl_xor(ai, off);
        float nm = fmaxf(m, om);
        s = s * expf(m - nm) + os * expf(om - nm);
        m = nm;
        if (oav > av || (oav == av && oi < ai)) { av = oav; ai = oi; }
    }
    float lse = m + logf(s);

    int pi[4];
#pragma unroll
    for (int p = 0; p < 4; ++p) pi[p] = pos[row * P_IDX + p];

    // positive dot-products: lane covers 8 consecutive d-elements
    const float4* q4 = (const float4*)(Q + (size_t)row * D_DIM);
    float4 qa = q4[lane * 2], qb = q4[lane * 2 + 1];
    float d[4];
#pragma unroll
    for (int p = 0; p < 4; ++p) {
        const float4* k4 = (const float4*)(K + (size_t)pi[p] * D_DIM);
        float4 ka = k4[lane * 2], kb = k4[lane * 2 + 1];
        d[p] = qa.x * ka.x + qa.y * ka.y + qa.z * ka.z + qa.w * ka.w
             + qb.x * kb.x + qb.y * kb.y + qb.z * kb.z + qb.w * kb.w;
    }
#pragma unroll
    for (int off = 32; off >= 1; off >>= 1) {
#pragma unroll
        for (int p = 0; p < 4; ++p) d[p] += __shfl_xor(d[p], off);
    }

    if (lane == 0) {
        float ps[4];
#pragma unroll
        for (int p = 0; p < 4; ++p) ps[p] = d[p] * INV_TEMP;
        // duplicate indices collapse in the reference's boolean mask
        const bool v1 = (pi[1] != pi[0]);
        const bool v2 = (pi[2] != pi[0]) && (pi[2] != pi[1]);
        const bool v3 = (pi[3] != pi[0]) && (pi[3] != pi[1]) && (pi[3] != pi[2]);
        float pm = ps[0];
        if (v1) pm = fmaxf(pm, ps[1]);
        if (v2) pm = fmaxf(pm, ps[2]);
        if (v3) pm = fmaxf(pm, ps[3]);
        float pse = expf(ps[0] - pm);
        if (v1) pse += expf(ps[1] - pm);
        if (v2) pse += expf(ps[2] - pm);
        if (v3) pse += expf(ps[3] - pm);
        float pos_lse = pm + logf(pse);
        logp[row] = pos_lse - lse;
        bool corr = (ai == pi[0]) || (ai == pi[1]) || (ai == pi[2]) || (ai == pi[3]);
        corrects[row] = corr ? 1.0f : 0.0f;
    }
}

// ---------------------------------------------------------------------------
// Kernel C: deterministic fixed-order reduction of logp -> loss
// ---------------------------------------------------------------------------
__global__ __launch_bounds__(256)
void loss_kernel(const float* __restrict__ logp, float* __restrict__ out)
{
    __shared__ float sm[256];
    const int t = threadIdx.x;
    float s = 0.f;
    for (int i = t; i < N_Q; i += 256) s += logp[i];
    sm[t] = s;
    __syncthreads();
    for (int off = 128; off >= 1; off >>= 1) {
        if (t < off) sm[t] += sm[t + off];
        __syncthreads();
    }
    if (t == 0) out[0] = -sm[0];
}

// ---------------------------------------------------------------------------
extern "C" void kernel_launch(void* const* d_in, const int* in_sizes, int n_in,
                              void* d_out, int out_size, void* d_ws, size_t ws_size,
                              hipStream_t stream)
{
    const float* Q = (const float*)d_in[0];
    const float* K = (const float*)d_in[1];
    const int* pos = (const int*)d_in[2];
    const int* ign = (const int*)d_in[3];
    float* out = (float*)d_out;

    float4* part = (float4*)d_ws;                                   // 4096*64*16B = 4 MB
    float* logp = (float*)((char*)d_ws + (size_t)N_Q * NCHUNK * sizeof(float4));

    dim3 gridA(N_Q / BM, M_K / BN);   // 32 x 64 = 2048 blocks
    scores_kernel<<<gridA, 256, 0, stream>>>(Q, K, ign, part);
    combine_kernel<<<N_Q, 64, 0, stream>>>(part, Q, K, pos, logp, out + 1);
    loss_kernel<<<1, 256, 0, stream>>>(logp, out);
}

// Round 2
// 211.547 us; speedup vs baseline: 2.0582x; 2.0582x over previous
//
#include <hip/hip_runtime.h>
#include <math.h>

// Problem constants (from reference)
#define N_Q 4096
#define M_K 8192
#define D_DIM 512
#define P_IDX 4
#define INV_TEMP 10.0f

#define NCHUNK 128          // 8192 / 64 cols per wave-chunk

typedef __attribute__((ext_vector_type(8))) short short8;
typedef __attribute__((ext_vector_type(4))) float f32x4;

__device__ __forceinline__ unsigned short bf16_rn(float x) {
    unsigned u = __float_as_uint(x);
    u += 0x7fffu + ((u >> 16) & 1u);
    return (unsigned short)(u >> 16);
}
__device__ __forceinline__ float bf16_f(unsigned short b) {
    return __uint_as_float(((unsigned)b) << 16);
}

// ---------------------------------------------------------------------------
// Split fp32 -> (hi, lo) bf16 pair.  a = hi + lo + O(2^-16 |a|).
// ---------------------------------------------------------------------------
__global__ __launch_bounds__(256)
void split_kernel(const float* __restrict__ x, unsigned short* __restrict__ hi,
                  unsigned short* __restrict__ lo, int n4)
{
    int i = blockIdx.x * 256 + threadIdx.x;
    if (i >= n4) return;
    float4 v = ((const float4*)x)[i];
    ushort4 h, l;
    h.x = bf16_rn(v.x); l.x = bf16_rn(v.x - bf16_f(h.x));
    h.y = bf16_rn(v.y); l.y = bf16_rn(v.y - bf16_f(h.y));
    h.z = bf16_rn(v.z); l.z = bf16_rn(v.z - bf16_f(h.z));
    h.w = bf16_rn(v.w); l.w = bf16_rn(v.w - bf16_f(h.w));
    ((ushort4*)hi)[i] = h;
    ((ushort4*)lo)[i] = l;
}

__device__ __forceinline__ void gload16(const void* g, const void* l) {
    __builtin_amdgcn_global_load_lds(
        (const __attribute__((address_space(1))) unsigned int*)g,
        (__attribute__((address_space(3))) unsigned int*)l, 16, 0, 0);
}

// ---------------------------------------------------------------------------
// bf16x3 MFMA GEMM (128x128 tile, BK=32) + fused scale/ignore-mask/
// per-64col-chunk {max, sumexp, argmax} partials.
// Grid (32, 64), block 256 = 4 waves (2x2), each wave owns 64x64.
// ---------------------------------------------------------------------------
__global__ __launch_bounds__(256)
void scores_mfma(const unsigned short* __restrict__ Qhi, const unsigned short* __restrict__ Qlo,
                 const unsigned short* __restrict__ Khi, const unsigned short* __restrict__ Klo,
                 const int* __restrict__ ign, float4* __restrict__ part)
{
    // 4 tiles (Ahi,Alo,Bhi,Blo), each 128 rows x 32 k stored plane-major:
    // chunk index c = kslot*128 + row, 8 bf16 (16 B) per chunk.  32 KB total.
    __shared__ __align__(16) unsigned short smem[4 * 4096];
    __shared__ int ign_s[128][P_IDX];

    const int tid = threadIdx.x;
    const int lane = tid & 63;
    const int wave = tid >> 6;
    const int wr = wave >> 1, wc = wave & 1;
    const int g = lane >> 4, cx = lane & 15;
    const int row0 = blockIdx.x * 128;
    const int col0 = blockIdx.y * 128;

    {   // stage ignore indices (512 ints, 2 per thread)
        int i0 = tid * 2;
        ign_s[i0 >> 2][i0 & 3] = ign[(size_t)(row0 + (i0 >> 2)) * P_IDX + (i0 & 3)];
        int i1 = i0 + 1;
        ign_s[i1 >> 2][i1 & 3] = ign[(size_t)(row0 + (i1 >> 2)) * P_IDX + (i1 & 3)];
    }

    f32x4 acc[4][4];
#pragma unroll
    for (int i = 0; i < 4; ++i)
#pragma unroll
        for (int j = 0; j < 4; ++j) acc[i][j] = (f32x4)0.f;

    for (int k0 = 0; k0 < D_DIM; k0 += 32) {
        __syncthreads();
        // stage 4 tiles: issue it covers chunks c = (it&1)*256 + tid of tile it>>1
#pragma unroll
        for (int it = 0; it < 8; ++it) {
            const int c = (it & 1) * 256 + tid;    // 0..511 within tile
            const int s = c >> 7;                  // k-slot 0..3
            const int r = c & 127;                 // row within tile
            const unsigned short* base =
                (it < 2) ? Qhi : (it < 4) ? Qlo : (it < 6) ? Khi : Klo;
            const int grow = ((it < 4) ? row0 : col0) + r;
            gload16(base + (size_t)grow * D_DIM + k0 + s * 8,
                    &smem[(it * 256 + tid) * 8]);
        }
        __syncthreads();

        short8 ah[4], al[4], bh[4], bl[4];
#pragma unroll
        for (int i = 0; i < 4; ++i) {
            const int ra = wr * 64 + i * 16 + cx;
            const int oa = (g * 128 + ra) * 8;
            ah[i] = *(const short8*)&smem[0 * 4096 + oa];
            al[i] = *(const short8*)&smem[1 * 4096 + oa];
            const int rb = wc * 64 + i * 16 + cx;
            const int ob = (g * 128 + rb) * 8;
            bh[i] = *(const short8*)&smem[2 * 4096 + ob];
            bl[i] = *(const short8*)&smem[3 * 4096 + ob];
        }
#pragma unroll
        for (int i = 0; i < 4; ++i)
#pragma unroll
            for (int j = 0; j < 4; ++j)
                acc[i][j] = __builtin_amdgcn_mfma_f32_16x16x32_bf16(ah[i], bh[j], acc[i][j], 0, 0, 0);
#pragma unroll
        for (int i = 0; i < 4; ++i)
#pragma unroll
            for (int j = 0; j < 4; ++j)
                acc[i][j] = __builtin_amdgcn_mfma_f32_16x16x32_bf16(ah[i], bl[j], acc[i][j], 0, 0, 0);
#pragma unroll
        for (int i = 0; i < 4; ++i)
#pragma unroll
            for (int j = 0; j < 4; ++j)
                acc[i][j] = __builtin_amdgcn_mfma_f32_16x16x32_bf16(al[i], bh[j], acc[i][j], 0, 0, 0);
    }

    // Epilogue: C row = wr*64 + i*16 + g*4 + t; col = wc*64 + j*16 + cx.
    // Per row: 16 lanes of group g hold 4 j-values each -> xor-reduce over 16.
#pragma unroll
    for (int i = 0; i < 4; ++i) {
#pragma unroll
        for (int t = 0; t < 4; ++t) {
            const int rl = wr * 64 + i * 16 + g * 4 + t;
            const int ig0 = ign_s[rl][0], ig1 = ign_s[rl][1];
            const int ig2 = ign_s[rl][2], ig3 = ign_s[rl][3];
            float v[4];
            float bm = -INFINITY; int bi = 0x7fffffff;
#pragma unroll
            for (int j = 0; j < 4; ++j) {
                const int col = col0 + wc * 64 + j * 16 + cx;
                float x = acc[i][j][t] * INV_TEMP;
                if (col == ig0 || col == ig1 || col == ig2 || col == ig3) x = -INFINITY;
                v[j] = x;
                if (x > bm) { bm = x; bi = col; }
            }
#pragma unroll
            for (int off = 8; off >= 1; off >>= 1) {
                float om = __shfl_xor(bm, off);
                int oi = __shfl_xor(bi, off);
                if (om > bm || (om == bm && oi < bi)) { bm = om; bi = oi; }
            }
            float se = 0.f;
#pragma unroll
            for (int j = 0; j < 4; ++j) se += expf(v[j] - bm); // exp(-inf - finite) = 0
#pragma unroll
            for (int off = 8; off >= 1; off >>= 1) se += __shfl_xor(se, off);
            if (cx == 0)
                part[(size_t)(row0 + rl) * NCHUNK + blockIdx.y * 2 + wc] =
                    make_float4(bm, se, __int_as_float(bi), 0.f);
        }
    }
}

// ---------------------------------------------------------------------------
// Kernel B: one wave per row.  Merge 128 chunk partials -> lse + argmax;
// positives recomputed exactly in fp32 (with duplicate dedup).
// ---------------------------------------------------------------------------
__global__ __launch_bounds__(64)
void combine_kernel(const float4* __restrict__ part,
                    const float* __restrict__ Q, const float* __restrict__ K,
                    const int* __restrict__ pos,
                    float* __restrict__ logp, float* __restrict__ corrects)
{
    const int row = blockIdx.x;
    const int lane = threadIdx.x;

    float4 p0 = part[(size_t)row * NCHUNK + lane];
    float4 p1 = part[(size_t)row * NCHUNK + 64 + lane];
    float m, s, av; int ai;
    if (p0.x >= p1.x) { av = p0.x; ai = __float_as_int(p0.z); }
    else              { av = p1.x; ai = __float_as_int(p1.z); }
    m = fmaxf(p0.x, p1.x);
    s = p0.y * expf(p0.x - m) + p1.y * expf(p1.x - m);

#pragma unroll
    for (int off = 32; off >= 1; off >>= 1) {
        float om = __shfl_xor(m, off);
        float os = __shfl_xor(s, off);
        float oav = __shfl_xor(av, off);
        int oi = __shfl_xor(ai, off);
        float nm = fmaxf(m, om);
        s = s * expf(m - nm) + os * expf(om - nm);
        m = nm;
        if (oav > av || (oav == av && oi < ai)) { av = oav; ai = oi; }
    }
    float lse = m + logf(s);

    int pi[4];
#pragma unroll
    for (int p = 0; p < 4; ++p) pi[p] = pos[row * P_IDX + p];

    // positive dot-products in exact fp32: lane covers 8 consecutive d-elements
    const float4* q4 = (const float4*)(Q + (size_t)row * D_DIM);
    float4 qa = q4[lane * 2], qb = q4[lane * 2 + 1];
    float d[4];
#pragma unroll
    for (int p = 0; p < 4; ++p) {
        const float4* k4 = (const float4*)(K + (size_t)pi[p] * D_DIM);
        float4 ka = k4[lane * 2], kb = k4[lane * 2 + 1];
        d[p] = qa.x * ka.x + qa.y * ka.y + qa.z * ka.z + qa.w * ka.w
             + qb.x * kb.x + qb.y * kb.y + qb.z * kb.z + qb.w * kb.w;
    }
#pragma unroll
    for (int off = 32; off >= 1; off >>= 1) {
#pragma unroll
        for (int p = 0; p < 4; ++p) d[p] += __shfl_xor(d[p], off);
    }

    if (lane == 0) {
        float ps[4];
#pragma unroll
        for (int p = 0; p < 4; ++p) ps[p] = d[p] * INV_TEMP;
        const bool v1 = (pi[1] != pi[0]);
        const bool v2 = (pi[2] != pi[0]) && (pi[2] != pi[1]);
        const bool v3 = (pi[3] != pi[0]) && (pi[3] != pi[1]) && (pi[3] != pi[2]);
        float pm = ps[0];
        if (v1) pm = fmaxf(pm, ps[1]);
        if (v2) pm = fmaxf(pm, ps[2]);
        if (v3) pm = fmaxf(pm, ps[3]);
        float pse = expf(ps[0] - pm);
        if (v1) pse += expf(ps[1] - pm);
        if (v2) pse += expf(ps[2] - pm);
        if (v3) pse += expf(ps[3] - pm);
        float pos_lse = pm + logf(pse);
        logp[row] = pos_lse - lse;
        bool corr = (ai == pi[0]) || (ai == pi[1]) || (ai == pi[2]) || (ai == pi[3]);
        corrects[row] = corr ? 1.0f : 0.0f;
    }
}

// ---------------------------------------------------------------------------
// Kernel C: deterministic fixed-order reduction of logp -> loss
// ---------------------------------------------------------------------------
__global__ __launch_bounds__(256)
void loss_kernel(const float* __restrict__ logp, float* __restrict__ out)
{
    __shared__ float sm[256];
    const int t = threadIdx.x;
    float s = 0.f;
    for (int i = t; i < N_Q; i += 256) s += logp[i];
    sm[t] = s;
    __syncthreads();
    for (int off = 128; off >= 1; off >>= 1) {
        if (t < off) sm[t] += sm[t + off];
        __syncthreads();
    }
    if (t == 0) out[0] = -sm[0];
}

// ---------------------------------------------------------------------------
extern "C" void kernel_launch(void* const* d_in, const int* in_sizes, int n_in,
                              void* d_out, int out_size, void* d_ws, size_t ws_size,
                              hipStream_t stream)
{
    const float* Q = (const float*)d_in[0];
    const float* K = (const float*)d_in[1];
    const int* pos = (const int*)d_in[2];
    const int* ign = (const int*)d_in[3];
    float* out = (float*)d_out;

    // workspace layout (total ~32.02 MB)
    unsigned short* Qhi = (unsigned short*)d_ws;                 // 4 MB
    unsigned short* Qlo = Qhi + (size_t)N_Q * D_DIM;             // 4 MB
    unsigned short* Khi = Qlo + (size_t)N_Q * D_DIM;             // 8 MB
    unsigned short* Klo = Khi + (size_t)M_K * D_DIM;             // 8 MB
    float4* part = (float4*)(Klo + (size_t)M_K * D_DIM);         // 8 MB
    float* logp = (float*)(part + (size_t)N_Q * NCHUNK);         // 16 KB

    const int nq4 = N_Q * D_DIM / 4;
    const int nk4 = M_K * D_DIM / 4;
    split_kernel<<<nq4 / 256, 256, 0, stream>>>(Q, Qhi, Qlo, nq4);
    split_kernel<<<nk4 / 256, 256, 0, stream>>>(K, Khi, Klo, nk4);

    dim3 gridA(N_Q / 128, M_K / 128);   // 32 x 64
    scores_mfma<<<gridA, 256, 0, stream>>>(Qhi, Qlo, Khi, Klo, ign, part);
    combine_kernel<<<N_Q, 64, 0, stream>>>(part, Q, K, pos, logp, out + 1);
    loss_kernel<<<1, 256, 0, stream>>>(logp, out);
}